// Round 11
// baseline (527.343 us; speedup 1.0000x reference)
//
#include <hip/hip_runtime.h>
#include <hip/hip_bf16.h>

// B=8, C=512, H=W=64, NH=8, HD=64, WIN=64, NW=64.
// Token matrix = x viewed as [32768][512] fp32 (raw reshape).
//   phase 0: zero window-counters; convert X->bf16, W->Wcat bf16
//   phase 1: FUSED kernel: QKV GEMM (256x256 tile, BK=64, drift schedule,
//            validated r5) + per-window attention tail: after epilogue each
//            block atomicAdds the 4 windows of its m-tile; the 6th contributor
//            of a window runs that window's attention (8 heads, 1/wave) with
//            QKV read from L2 (same-XCD swizzle) and writes fp32 out.
// ws: Wc@0 | Xb@2MiB | cnt@35MiB | Q@36MiB | K@68MiB | V^T@100MiB (132MiB).

typedef __attribute__((ext_vector_type(8))) short bf16x8;
typedef __attribute__((ext_vector_type(4))) float f32x4;

#define GLDS(gp, lp) __builtin_amdgcn_global_load_lds( \
    (const __attribute__((address_space(1))) unsigned int*)(gp), \
    (__attribute__((address_space(3))) unsigned int*)(lp), 16, 0, 0)

__device__ __forceinline__ unsigned short f2bf(float f) {
  union { __hip_bfloat16 h; unsigned short u; } v;
  v.h = __float2bfloat16(f);               // v_cvt_pk_bf16_f32 (RNE)
  return v.u;
}

// ---------- zero the 512 per-window counters (every launch) ----------
__global__ __launch_bounds__(256) void zero_cnt(int* __restrict__ c) {
  c[blockIdx.x * 256 + threadIdx.x] = 0;
}

// ---------- prep: X fp32->bf16 and W{q,k,v} -> Wcat bf16 (validated) ----------
__global__ __launch_bounds__(256) void prep_convert(
    const float* __restrict__ X, const float* __restrict__ Wq,
    const float* __restrict__ Wk, const float* __restrict__ Wv,
    unsigned short* __restrict__ Xb, unsigned short* __restrict__ Wc) {
  const unsigned int i = blockIdx.x * 256 + threadIdx.x;
  const float* src;
  unsigned short* dst;
  if (i < 2097152u) {                       // X: 16.7M floats, 8 per thread
    src = X + (size_t)i * 8;
    dst = Xb + (size_t)i * 8;
  } else {                                  // Wcat: [1536][512]
    const unsigned int j = i - 2097152u;    // < 98304
    const unsigned int e = j * 8;
    const unsigned int n = e >> 9, kk = e & 511;
    src = ((n < 512) ? Wq : (n < 1024 ? Wk : Wv)) + (size_t)(n & 511) * 512 + kk;
    dst = Wc + (size_t)n * 512 + kk;
  }
  float4 f0 = *(const float4*)(src);
  float4 f1 = *(const float4*)(src + 4);
  __align__(16) unsigned short u[8];
  u[0] = f2bf(f0.x); u[1] = f2bf(f0.y); u[2] = f2bf(f0.z); u[3] = f2bf(f0.w);
  u[4] = f2bf(f1.x); u[5] = f2bf(f1.y); u[6] = f2bf(f1.z); u[7] = f2bf(f1.w);
  *(bf16x8*)(dst) = *(const bf16x8*)(u);
}

// ---------- FUSED: QKV GEMM (r5 drift) + per-window attention tail ----------
__global__ __launch_bounds__(512, 2) void qkv_attn_fused(
    const unsigned short* __restrict__ Xb, const unsigned short* __restrict__ Wc,
    const float* __restrict__ bq, const float* __restrict__ bk,
    const float* __restrict__ bv, const float* __restrict__ Bb,
    unsigned short* __restrict__ Qo, unsigned short* __restrict__ Ko,
    unsigned short* __restrict__ Vo, float* __restrict__ out,
    int* __restrict__ cnt) {
  __shared__ __align__(16) char LDS[131072];

  const int tid  = threadIdx.x;
  const int lane = tid & 63;
  const int wid  = tid >> 6;
  const int wm = wid >> 2, wn = wid & 3;   // 2(M) x 4(N); wave tile 128x64

  // XCD-chunked swizzle: 768 = 8 x 96 works; n-tiles fastest within a chunk.
  const int work = (int)(blockIdx.x & 7) * 96 + (int)(blockIdx.x >> 3);
  const int bx = work % 6, by = work / 6;
  const int n0 = bx * 256, m0 = by * 256;

  // --- staging addressing (linear LDS dest; inverse-swizzled global source) ---
  const int lcol  = ((lane & 3) * 8) ^ ((lane >= 32) ? 16 : 0);   // elements
  const int arow0 = (wid >> 1) * 16 + (lane >> 2);                // 0..63
  const int acol0 = (wid & 1) * 32 + lcol;

#define STAGE_A(half, tt) do { \
    const unsigned short* g = Xb + (size_t)(m0 + (half) * 128 + arow0) * 512 + (tt) * 64 + acol0; \
    char* l = LDS + ((tt) & 1) * 32768 + (half) * 16384 + wid * 1024; \
    GLDS(g, l); \
    GLDS(g + 64 * 512, l + 8192); \
  } while (0)

#define STAGE_B(half, tt) do { \
    const unsigned short* g = Wc + (size_t)(n0 + (half) * 128 + arow0) * 512 + (tt) * 64 + acol0; \
    char* l = LDS + 65536 + ((tt) & 1) * 32768 + (half) * 16384 + wid * 1024; \
    GLDS(g, l); \
    GLDS(g + 64 * 512, l + 8192); \
  } while (0)

  // --- fragment-read addressing (st_16x32-swizzled; validated r3-r10) ---
  const int sloff = (((lane & 15) * 64) + ((lane >> 4) * 16)) ^ ((lane & 8) ? 32 : 0);
  char* const Ab = LDS + wm * 16384 + sloff;
  char* const Bb2 = LDS + 65536 + (wn >> 1) * 16384 + sloff;
  const int bfr = (wn & 1) * 4;   // B frag index base within half

  f32x4 acc[8][4];
#pragma unroll
  for (int i = 0; i < 8; ++i)
#pragma unroll
    for (int j = 0; j < 4; ++j) acc[i][j] = (f32x4){0.f, 0.f, 0.f, 0.f};

  // prologue: stage tile 0 into buf0
  STAGE_A(0, 0); STAGE_A(1, 0); STAGE_B(0, 0); STAGE_B(1, 0);
  asm volatile("s_waitcnt vmcnt(0)" ::: "memory");
  __builtin_amdgcn_s_barrier();

  for (int t = 0; t < 8; ++t) {
    const int bo = (t & 1) * 32768;
    if (t + 1 < 8) {                        // stage next tile into free buffer
      STAGE_A(0, t + 1); STAGE_A(1, t + 1);
      STAGE_B(0, t + 1); STAGE_B(1, t + 1);
    }
    {                                       // full-tile compute (r5, validated)
      bf16x8 a[8], b[4];
#pragma unroll
      for (int mi = 0; mi < 8; ++mi)
        a[mi] = *(const bf16x8*)(Ab + bo + mi * 2048);
#pragma unroll
      for (int ni = 0; ni < 4; ++ni)
        b[ni] = *(const bf16x8*)(Bb2 + bo + (bfr + ni) * 2048);
#pragma unroll
      for (int mi = 0; mi < 8; ++mi)
#pragma unroll
        for (int ni = 0; ni < 4; ++ni)
          acc[mi][ni] = __builtin_amdgcn_mfma_f32_16x16x32_bf16(
              a[mi], b[ni], acc[mi][ni], 0, 0, 0);
#pragma unroll
      for (int mi = 0; mi < 8; ++mi)
        a[mi] = *(const bf16x8*)(Ab + bo + mi * 2048 + 1024);
#pragma unroll
      for (int ni = 0; ni < 4; ++ni)
        b[ni] = *(const bf16x8*)(Bb2 + bo + (bfr + ni) * 2048 + 1024);
#pragma unroll
      for (int mi = 0; mi < 8; ++mi)
#pragma unroll
        for (int ni = 0; ni < 4; ++ni)
          acc[mi][ni] = __builtin_amdgcn_mfma_f32_16x16x32_bf16(
              a[mi], b[ni], acc[mi][ni], 0, 0, 0);
    }
    if (t + 1 < 8) asm volatile("s_waitcnt vmcnt(0)" ::: "memory");
    __builtin_amdgcn_s_barrier();
  }

  // ---- epilogue: LDS-staged, coalesced 16B stores (validated r4-r10) ----
  {
    const int p = n0 >> 9;                  // 0:Q 1:K 2:V (256-tile never spans)
    const float* bias = (p == 0) ? bq : (p == 1) ? bk : bv;
    const float qs = (p == 0) ? 0.125f : 1.0f;
    const int hi = lane >> 4, lr = lane & 15;
    const int h = ((n0 & 511) + wn * 64) >> 6;
    char* const scr = LDS + wid * 8192;
    float bsv[4];
#pragma unroll
    for (int ni = 0; ni < 4; ++ni)
      bsv[ni] = bias[(n0 & 511) + wn * 64 + ni * 16 + lr];

#pragma unroll
    for (int wh = 0; wh < 2; ++wh) {
      asm volatile("s_waitcnt lgkmcnt(0)" ::: "memory");  // WAR vs prev reads
      __builtin_amdgcn_sched_barrier(0);
      if (p < 2) {
#pragma unroll
        for (int f = 0; f < 4; ++f)
#pragma unroll
          for (int ni = 0; ni < 4; ++ni) {
            const int d = ni * 16 + lr;
#pragma unroll
            for (int rr = 0; rr < 4; ++rr) {
              const int t = f * 16 + hi * 4 + rr;
              const int off = t * 64 + (d ^ ((t & 7) << 3));
              *(unsigned short*)(scr + off * 2) =
                  f2bf((acc[wh * 4 + f][ni][rr] + bsv[ni]) * qs);
            }
          }
      } else {
#pragma unroll
        for (int f = 0; f < 4; ++f)
#pragma unroll
          for (int ni = 0; ni < 4; ++ni) {
            const int d = ni * 16 + lr;
            const int t0 = f * 16 + hi * 4;
            ushort4 pk;
            pk.x = f2bf(acc[wh * 4 + f][ni][0] + bsv[ni]);
            pk.y = f2bf(acc[wh * 4 + f][ni][1] + bsv[ni]);
            pk.z = f2bf(acc[wh * 4 + f][ni][2] + bsv[ni]);
            pk.w = f2bf(acc[wh * 4 + f][ni][3] + bsv[ni]);
            const int off = d * 64 + (t0 ^ ((d & 7) << 3));
            *(ushort4*)(scr + off * 2) = pk;
          }
      }
      asm volatile("s_waitcnt lgkmcnt(0)" ::: "memory");
      __builtin_amdgcn_sched_barrier(0);
      const int win = (m0 + wm * 128 + wh * 64) >> 6;
      unsigned short* dst =
          ((p == 0) ? Qo : (p == 1) ? Ko : Vo) + (size_t)(win * 8 + h) * 4096;
#pragma unroll
      for (int i = 0; i < 8; ++i) {
        const int r = i * 8 + (lane >> 3);
        const int c = lane & 7;
        const int off = r * 64 + ((c ^ (r & 7)) * 8);
        bf16x8 row = *(const bf16x8*)(scr + off * 2);
        *(bf16x8*)(dst + r * 64 + c * 8) = row;
      }
    }
  }

  // ---- per-window completion + attention tail ----
  __threadfence();                          // release this block's QKV stores
  __syncthreads();
  int* flags = (int*)(LDS + 130048);        // past all P buffers
  if (tid < 4) {
    const int old = atomicAdd(cnt + (by * 4 + tid), 1);
    flags[tid] = (old == 5) ? 1 : 0;        // 6th contributor runs attention
  }
  __syncthreads();
  __threadfence();                          // acquire other blocks' stores

  for (int wi = 0; wi < 4; ++wi) {
    if (!flags[wi]) continue;
    const int win = by * 4 + wi;
    const int h = wid;                      // 1 head per wave
    const size_t base = (size_t)(win * 8 + h) * 4096;
    const unsigned short* q = Qo + base;
    const unsigned short* k = Ko + base;
    const unsigned short* v = Vo + base;    // V^T: [d][t]
    unsigned short* const P = (unsigned short*)(LDS + wid * 16384);
    const int lr = lane & 15;
    const int hi = lane >> 4;

    bf16x8 qa[4][2], kb[4][2];
#pragma unroll
    for (int mt = 0; mt < 4; ++mt)
#pragma unroll
      for (int ks = 0; ks < 2; ++ks)
        qa[mt][ks] = *(const bf16x8*)(q + (size_t)(mt * 16 + lr) * 64 + ks * 32 + hi * 8);
#pragma unroll
    for (int nt = 0; nt < 4; ++nt)
#pragma unroll
      for (int ks = 0; ks < 2; ++ks)
        kb[nt][ks] = *(const bf16x8*)(k + (size_t)(nt * 16 + lr) * 64 + ks * 32 + hi * 8);

    f32x4 s[4][4];
#pragma unroll
    for (int mt = 0; mt < 4; ++mt)
#pragma unroll
      for (int nt = 0; nt < 4; ++nt) {
        s[mt][nt] = (f32x4){0.f, 0.f, 0.f, 0.f};
        s[mt][nt] = __builtin_amdgcn_mfma_f32_16x16x32_bf16(qa[mt][0], kb[nt][0], s[mt][nt], 0, 0, 0);
        s[mt][nt] = __builtin_amdgcn_mfma_f32_16x16x32_bf16(qa[mt][1], kb[nt][1], s[mt][nt], 0, 0, 0);
      }

#pragma unroll
    for (int mt = 0; mt < 4; ++mt)
#pragma unroll
      for (int nt = 0; nt < 4; ++nt)
#pragma unroll
        for (int rr = 0; rr < 4; ++rr)
          s[mt][nt][rr] += Bb[(mt * 16 + hi * 4 + rr) * 64 + nt * 16 + lr];

    float inv[4][4];
#pragma unroll
    for (int mt = 0; mt < 4; ++mt)
#pragma unroll
      for (int rr = 0; rr < 4; ++rr) {
        float m = fmaxf(fmaxf(s[mt][0][rr], s[mt][1][rr]),
                        fmaxf(s[mt][2][rr], s[mt][3][rr]));
        m = fmaxf(m, __shfl_xor(m, 1));
        m = fmaxf(m, __shfl_xor(m, 2));
        m = fmaxf(m, __shfl_xor(m, 4));
        m = fmaxf(m, __shfl_xor(m, 8));
        float sum = 0.f;
#pragma unroll
        for (int nt = 0; nt < 4; ++nt) {
          float e = __expf(s[mt][nt][rr] - m);
          s[mt][nt][rr] = e;
          sum += e;
        }
        sum += __shfl_xor(sum, 1);
        sum += __shfl_xor(sum, 2);
        sum += __shfl_xor(sum, 4);
        sum += __shfl_xor(sum, 8);
        inv[mt][rr] = 1.0f / sum;
      }

#pragma unroll
    for (int mt = 0; mt < 4; ++mt)
#pragma unroll
      for (int nt = 0; nt < 4; ++nt)
#pragma unroll
        for (int rr = 0; rr < 4; ++rr)
          P[(mt * 16 + hi * 4 + rr) * 72 + nt * 16 + lr] =
              f2bf(s[mt][nt][rr] * inv[mt][rr]);
    asm volatile("s_waitcnt lgkmcnt(0)" ::: "memory");  // wave-private buffer
    __builtin_amdgcn_sched_barrier(0);

    bf16x8 pa[4][2], vb[4][2];
#pragma unroll
    for (int mt = 0; mt < 4; ++mt)
#pragma unroll
      for (int ks = 0; ks < 2; ++ks)
        pa[mt][ks] = *(const bf16x8*)(&P[(mt * 16 + lr) * 72 + ks * 32 + hi * 8]);
#pragma unroll
    for (int nt = 0; nt < 4; ++nt)
#pragma unroll
      for (int ks = 0; ks < 2; ++ks)
        vb[nt][ks] = *(const bf16x8*)(v + (size_t)(nt * 16 + lr) * 64 + ks * 32 + hi * 8);

    f32x4 o[4][4];
#pragma unroll
    for (int mt = 0; mt < 4; ++mt)
#pragma unroll
      for (int nt = 0; nt < 4; ++nt) {
        o[mt][nt] = (f32x4){0.f, 0.f, 0.f, 0.f};
        o[mt][nt] = __builtin_amdgcn_mfma_f32_16x16x32_bf16(pa[mt][0], vb[nt][0], o[mt][nt], 0, 0, 0);
        o[mt][nt] = __builtin_amdgcn_mfma_f32_16x16x32_bf16(pa[mt][1], vb[nt][1], o[mt][nt], 0, 0, 0);
      }

    float* op = out + (size_t)win * 32768 + h * 64;
#pragma unroll
    for (int mt = 0; mt < 4; ++mt)
#pragma unroll
      for (int nt = 0; nt < 4; ++nt)
#pragma unroll
        for (int rr = 0; rr < 4; ++rr)
          op[(size_t)(mt * 16 + hi * 4 + rr) * 512 + nt * 16 + lr] = o[mt][nt][rr];
  }
#undef STAGE_A
#undef STAGE_B
}

extern "C" void kernel_launch(void* const* d_in, const int* in_sizes, int n_in,
                              void* d_out, int out_size, void* d_ws, size_t ws_size,
                              hipStream_t stream) {
  const float* x     = (const float*)d_in[0];
  const float* Wq    = (const float*)d_in[1];
  const float* bq    = (const float*)d_in[2];
  const float* Wk    = (const float*)d_in[3];
  const float* bk    = (const float*)d_in[4];
  const float* Wv    = (const float*)d_in[5];
  const float* bv    = (const float*)d_in[6];
  const float* Bbias = (const float*)d_in[7];
  float* out = (float*)d_out;

  // ws: Wc@0 | Xb@2MiB | cnt@35MiB | Q@36MiB | K@68MiB | V^T@100MiB
  unsigned short* Wc = (unsigned short*)d_ws;
  unsigned short* Xb = (unsigned short*)((char*)d_ws + ((size_t)2 << 20));
  int*            Cn = (int*)((char*)d_ws + ((size_t)35 << 20));
  unsigned short* Q  = (unsigned short*)((char*)d_ws + ((size_t)36 << 20));
  unsigned short* K  = (unsigned short*)((char*)d_ws + ((size_t)68 << 20));
  unsigned short* V  = (unsigned short*)((char*)d_ws + ((size_t)100 << 20));

  zero_cnt<<<dim3(2), dim3(256), 0, stream>>>(Cn);
  prep_convert<<<dim3(8576), dim3(256), 0, stream>>>(x, Wq, Wk, Wv, Xb, Wc);
  qkv_attn_fused<<<dim3(768), dim3(512), 0, stream>>>(
      Xb, Wc, bq, bk, bv, Bbias, Q, K, V, out, Cn);
}

// Round 12
// 113.259 us; speedup vs baseline: 4.6561x; 4.6561x over previous
//
#include <hip/hip_runtime.h>
#include <hip/hip_bf16.h>

// B=8, C=512, H=W=64, NH=8, HD=64, WIN=64, NW=64.
// Token matrix = x viewed as [32768][512] fp32 (raw reshape).
//   phase 0: convert X -> bf16, W{q,k,v} -> Wcat bf16 [1536][512]
//   phase 1: QKV GEMM M=32768 K=512 N=1536 — 256x256 tile, BK=64, 8 waves,
//            drift schedule (1 barrier/K-tile), T2 st_16x32 swizzle
//            (0 conflicts), LDS-staged coalesced epilogue.  [r5 best: 59.7us]
//   phase 2: per (window,head): S=Q@K^T(+bias), softmax, P@V
// ws: Wc@0 | Xb@2MiB | Q@36MiB | K@68MiB | V^T@100MiB (132MiB; fits).
// NOTE (r11 lesson): do NOT fuse attn via __threadfence producer/consumer —
// device-scope fences write back + invalidate the XCD L2 per block (L2s are
// not cross-XCD coherent), destroying tile locality: measured 527us, FETCH 2x.

typedef __attribute__((ext_vector_type(8))) short bf16x8;
typedef __attribute__((ext_vector_type(4))) float f32x4;

#define GLDS(gp, lp) __builtin_amdgcn_global_load_lds( \
    (const __attribute__((address_space(1))) unsigned int*)(gp), \
    (__attribute__((address_space(3))) unsigned int*)(lp), 16, 0, 0)

__device__ __forceinline__ unsigned short f2bf(float f) {
  union { __hip_bfloat16 h; unsigned short u; } v;
  v.h = __float2bfloat16(f);               // v_cvt_pk_bf16_f32 (RNE)
  return v.u;
}

// ---------- prep: X fp32->bf16 and W{q,k,v} -> Wcat bf16 ----------
__global__ __launch_bounds__(256) void prep_convert(
    const float* __restrict__ X, const float* __restrict__ Wq,
    const float* __restrict__ Wk, const float* __restrict__ Wv,
    unsigned short* __restrict__ Xb, unsigned short* __restrict__ Wc) {
  const unsigned int i = blockIdx.x * 256 + threadIdx.x;
  const float* src;
  unsigned short* dst;
  if (i < 2097152u) {                       // X: 16.7M floats, 8 per thread
    src = X + (size_t)i * 8;
    dst = Xb + (size_t)i * 8;
  } else {                                  // Wcat: [1536][512]
    const unsigned int j = i - 2097152u;    // < 98304
    const unsigned int e = j * 8;
    const unsigned int n = e >> 9, kk = e & 511;
    src = ((n < 512) ? Wq : (n < 1024 ? Wk : Wv)) + (size_t)(n & 511) * 512 + kk;
    dst = Wc + (size_t)n * 512 + kk;
  }
  float4 f0 = *(const float4*)(src);
  float4 f1 = *(const float4*)(src + 4);
  __align__(16) unsigned short u[8];
  u[0] = f2bf(f0.x); u[1] = f2bf(f0.y); u[2] = f2bf(f0.z); u[3] = f2bf(f0.w);
  u[4] = f2bf(f1.x); u[5] = f2bf(f1.y); u[6] = f2bf(f1.z); u[7] = f2bf(f1.w);
  *(bf16x8*)(dst) = *(const bf16x8*)(u);
}

// ---------- QKV GEMM: 256x256 tile, BK=64, 8 waves, drift schedule ----------
// Per K-tile: stage all 8 GLDS for t+1 into buf[t^1], then plain
// ds_read+MFMA (compiler-scheduled, waves drift), then vmcnt(0)+one barrier.
__global__ __launch_bounds__(512, 2) void qkv_gemm_256(
    const unsigned short* __restrict__ Xb, const unsigned short* __restrict__ Wc,
    const float* __restrict__ bq, const float* __restrict__ bk,
    const float* __restrict__ bv,
    unsigned short* __restrict__ Qo, unsigned short* __restrict__ Ko,
    unsigned short* __restrict__ Vo) {
  __shared__ __align__(16) char LDS[131072];

  const int tid  = threadIdx.x;
  const int lane = tid & 63;
  const int wid  = tid >> 6;
  const int wm = wid >> 2, wn = wid & 3;   // 2(M) x 4(N); wave tile 128x64

  // XCD-chunked swizzle: 768 = 8 x 96 works; n-tiles fastest within a chunk.
  const int work = (int)(blockIdx.x & 7) * 96 + (int)(blockIdx.x >> 3);
  const int bx = work % 6, by = work / 6;
  const int n0 = bx * 256, m0 = by * 256;

  // --- staging addressing (linear LDS dest; inverse-swizzled global source) ---
  const int lcol  = ((lane & 3) * 8) ^ ((lane >= 32) ? 16 : 0);   // elements
  const int arow0 = (wid >> 1) * 16 + (lane >> 2);                // 0..63
  const int acol0 = (wid & 1) * 32 + lcol;

#define STAGE_A(half, tt) do { \
    const unsigned short* g = Xb + (size_t)(m0 + (half) * 128 + arow0) * 512 + (tt) * 64 + acol0; \
    char* l = LDS + ((tt) & 1) * 32768 + (half) * 16384 + wid * 1024; \
    GLDS(g, l); \
    GLDS(g + 64 * 512, l + 8192); \
  } while (0)

#define STAGE_B(half, tt) do { \
    const unsigned short* g = Wc + (size_t)(n0 + (half) * 128 + arow0) * 512 + (tt) * 64 + acol0; \
    char* l = LDS + 65536 + ((tt) & 1) * 32768 + (half) * 16384 + wid * 1024; \
    GLDS(g, l); \
    GLDS(g + 64 * 512, l + 8192); \
  } while (0)

  // --- fragment-read addressing (st_16x32-swizzled; validated r3-r10) ---
  const int sloff = (((lane & 15) * 64) + ((lane >> 4) * 16)) ^ ((lane & 8) ? 32 : 0);
  char* const Ab = LDS + wm * 16384 + sloff;
  char* const Bb2 = LDS + 65536 + (wn >> 1) * 16384 + sloff;
  const int bfr = (wn & 1) * 4;   // B frag index base within half

  f32x4 acc[8][4];
#pragma unroll
  for (int i = 0; i < 8; ++i)
#pragma unroll
    for (int j = 0; j < 4; ++j) acc[i][j] = (f32x4){0.f, 0.f, 0.f, 0.f};

  // prologue: stage tile 0 into buf0
  STAGE_A(0, 0); STAGE_A(1, 0); STAGE_B(0, 0); STAGE_B(1, 0);
  asm volatile("s_waitcnt vmcnt(0)" ::: "memory");
  __builtin_amdgcn_s_barrier();

  for (int t = 0; t < 8; ++t) {
    const int bo = (t & 1) * 32768;
    if (t + 1 < 8) {                        // stage next tile into free buffer
      STAGE_A(0, t + 1); STAGE_A(1, t + 1);
      STAGE_B(0, t + 1); STAGE_B(1, t + 1);
    }
    {                                       // full-tile compute, no barriers
      bf16x8 a[8], b[4];
#pragma unroll
      for (int mi = 0; mi < 8; ++mi)
        a[mi] = *(const bf16x8*)(Ab + bo + mi * 2048);
#pragma unroll
      for (int ni = 0; ni < 4; ++ni)
        b[ni] = *(const bf16x8*)(Bb2 + bo + (bfr + ni) * 2048);
#pragma unroll
      for (int mi = 0; mi < 8; ++mi)
#pragma unroll
        for (int ni = 0; ni < 4; ++ni)
          acc[mi][ni] = __builtin_amdgcn_mfma_f32_16x16x32_bf16(
              a[mi], b[ni], acc[mi][ni], 0, 0, 0);
#pragma unroll
      for (int mi = 0; mi < 8; ++mi)
        a[mi] = *(const bf16x8*)(Ab + bo + mi * 2048 + 1024);
#pragma unroll
      for (int ni = 0; ni < 4; ++ni)
        b[ni] = *(const bf16x8*)(Bb2 + bo + (bfr + ni) * 2048 + 1024);
#pragma unroll
      for (int mi = 0; mi < 8; ++mi)
#pragma unroll
        for (int ni = 0; ni < 4; ++ni)
          acc[mi][ni] = __builtin_amdgcn_mfma_f32_16x16x32_bf16(
              a[mi], b[ni], acc[mi][ni], 0, 0, 0);
    }
    if (t + 1 < 8) asm volatile("s_waitcnt vmcnt(0)" ::: "memory");
    __builtin_amdgcn_s_barrier();
  }

  // ---- epilogue: LDS-staged, coalesced 16B stores (validated r4-r10) ----
  {
    const int p = n0 >> 9;                  // 0:Q 1:K 2:V (256-tile never spans)
    const float* bias = (p == 0) ? bq : (p == 1) ? bk : bv;
    const float qs = (p == 0) ? 0.125f : 1.0f;
    const int hi = lane >> 4, lr = lane & 15;
    const int h = ((n0 & 511) + wn * 64) >> 6;
    char* const scr = LDS + wid * 8192;
    float bsv[4];
#pragma unroll
    for (int ni = 0; ni < 4; ++ni)
      bsv[ni] = bias[(n0 & 511) + wn * 64 + ni * 16 + lr];

#pragma unroll
    for (int wh = 0; wh < 2; ++wh) {
      asm volatile("s_waitcnt lgkmcnt(0)" ::: "memory");  // WAR vs prev reads
      __builtin_amdgcn_sched_barrier(0);
      if (p < 2) {
        // T[t][d]: thread writes (t = f*16+hi*4+rr, d = ni*16+lr)
#pragma unroll
        for (int f = 0; f < 4; ++f)
#pragma unroll
          for (int ni = 0; ni < 4; ++ni) {
            const int d = ni * 16 + lr;
#pragma unroll
            for (int rr = 0; rr < 4; ++rr) {
              const int t = f * 16 + hi * 4 + rr;
              const int off = t * 64 + (d ^ ((t & 7) << 3));
              *(unsigned short*)(scr + off * 2) =
                  f2bf((acc[wh * 4 + f][ni][rr] + bsv[ni]) * qs);
            }
          }
      } else {
        // T'[d][t]: thread packs 4 consecutive t (rr) at fixed d -> b64
#pragma unroll
        for (int f = 0; f < 4; ++f)
#pragma unroll
          for (int ni = 0; ni < 4; ++ni) {
            const int d = ni * 16 + lr;
            const int t0 = f * 16 + hi * 4;
            ushort4 pk;
            pk.x = f2bf(acc[wh * 4 + f][ni][0] + bsv[ni]);
            pk.y = f2bf(acc[wh * 4 + f][ni][1] + bsv[ni]);
            pk.z = f2bf(acc[wh * 4 + f][ni][2] + bsv[ni]);
            pk.w = f2bf(acc[wh * 4 + f][ni][3] + bsv[ni]);
            const int off = d * 64 + (t0 ^ ((d & 7) << 3));
            *(ushort4*)(scr + off * 2) = pk;
          }
      }
      asm volatile("s_waitcnt lgkmcnt(0)" ::: "memory");  // writes -> readable
      __builtin_amdgcn_sched_barrier(0);
      const int win = (m0 + wm * 128 + wh * 64) >> 6;
      unsigned short* dst =
          ((p == 0) ? Qo : (p == 1) ? Ko : Vo) + (size_t)(win * 8 + h) * 4096;
#pragma unroll
      for (int i = 0; i < 8; ++i) {
        const int r = i * 8 + (lane >> 3);
        const int c = lane & 7;
        const int off = r * 64 + ((c ^ (r & 7)) * 8);
        bf16x8 row = *(const bf16x8*)(scr + off * 2);   // ds_read_b128
        *(bf16x8*)(dst + r * 64 + c * 8) = row;         // coalesced 16B store
      }
    }
  }
#undef STAGE_A
#undef STAGE_B
}

// ---------- attention: 1 wave per (window, head) ----------
__global__ __launch_bounds__(64) void attn_win(
    const unsigned short* __restrict__ Qp, const unsigned short* __restrict__ Kp,
    const unsigned short* __restrict__ Vp, const float* __restrict__ Bb,
    float* __restrict__ out) {
  __shared__ __align__(16) unsigned short P[64 * 72];
  const int lane = threadIdx.x;
  const int win = blockIdx.x >> 3;
  const int h   = blockIdx.x & 7;
  const size_t base = (size_t)(win * 8 + h) * 4096;
  const unsigned short* q = Qp + base;
  const unsigned short* k = Kp + base;
  const unsigned short* v = Vp + base;   // V^T: [d][t]
  const int lr = lane & 15;
  const int hi = lane >> 4;

  bf16x8 qa[4][2], kb[4][2];
#pragma unroll
  for (int mt = 0; mt < 4; ++mt)
#pragma unroll
    for (int ks = 0; ks < 2; ++ks)
      qa[mt][ks] = *(const bf16x8*)(q + (size_t)(mt * 16 + lr) * 64 + ks * 32 + hi * 8);
#pragma unroll
  for (int nt = 0; nt < 4; ++nt)
#pragma unroll
    for (int ks = 0; ks < 2; ++ks)
      kb[nt][ks] = *(const bf16x8*)(k + (size_t)(nt * 16 + lr) * 64 + ks * 32 + hi * 8);

  f32x4 s[4][4];
#pragma unroll
  for (int mt = 0; mt < 4; ++mt)
#pragma unroll
    for (int nt = 0; nt < 4; ++nt) {
      s[mt][nt] = (f32x4){0.f, 0.f, 0.f, 0.f};
      s[mt][nt] = __builtin_amdgcn_mfma_f32_16x16x32_bf16(qa[mt][0], kb[nt][0], s[mt][nt], 0, 0, 0);
      s[mt][nt] = __builtin_amdgcn_mfma_f32_16x16x32_bf16(qa[mt][1], kb[nt][1], s[mt][nt], 0, 0, 0);
    }

#pragma unroll
  for (int mt = 0; mt < 4; ++mt)
#pragma unroll
    for (int nt = 0; nt < 4; ++nt)
#pragma unroll
      for (int rr = 0; rr < 4; ++rr)
        s[mt][nt][rr] += Bb[(mt * 16 + hi * 4 + rr) * 64 + nt * 16 + lr];

  float inv[4][4];
#pragma unroll
  for (int mt = 0; mt < 4; ++mt)
#pragma unroll
    for (int rr = 0; rr < 4; ++rr) {
      float m = fmaxf(fmaxf(s[mt][0][rr], s[mt][1][rr]),
                      fmaxf(s[mt][2][rr], s[mt][3][rr]));
      m = fmaxf(m, __shfl_xor(m, 1));
      m = fmaxf(m, __shfl_xor(m, 2));
      m = fmaxf(m, __shfl_xor(m, 4));
      m = fmaxf(m, __shfl_xor(m, 8));
      float sum = 0.f;
#pragma unroll
      for (int nt = 0; nt < 4; ++nt) {
        float e = __expf(s[mt][nt][rr] - m);
        s[mt][nt][rr] = e;
        sum += e;
      }
      sum += __shfl_xor(sum, 1);
      sum += __shfl_xor(sum, 2);
      sum += __shfl_xor(sum, 4);
      sum += __shfl_xor(sum, 8);
      inv[mt][rr] = 1.0f / sum;
    }

#pragma unroll
  for (int mt = 0; mt < 4; ++mt)
#pragma unroll
    for (int nt = 0; nt < 4; ++nt)
#pragma unroll
      for (int rr = 0; rr < 4; ++rr)
        P[(mt * 16 + hi * 4 + rr) * 72 + nt * 16 + lr] =
            f2bf(s[mt][nt][rr] * inv[mt][rr]);
  __syncthreads();

  bf16x8 pa[4][2], vb[4][2];
#pragma unroll
  for (int mt = 0; mt < 4; ++mt)
#pragma unroll
    for (int ks = 0; ks < 2; ++ks)
      pa[mt][ks] = *(const bf16x8*)(&P[(mt * 16 + lr) * 72 + ks * 32 + hi * 8]);
#pragma unroll
  for (int nt = 0; nt < 4; ++nt)
#pragma unroll
    for (int ks = 0; ks < 2; ++ks)
      vb[nt][ks] = *(const bf16x8*)(v + (size_t)(nt * 16 + lr) * 64 + ks * 32 + hi * 8);

  f32x4 o[4][4];
#pragma unroll
  for (int mt = 0; mt < 4; ++mt)
#pragma unroll
    for (int nt = 0; nt < 4; ++nt) {
      o[mt][nt] = (f32x4){0.f, 0.f, 0.f, 0.f};
      o[mt][nt] = __builtin_amdgcn_mfma_f32_16x16x32_bf16(pa[mt][0], vb[nt][0], o[mt][nt], 0, 0, 0);
      o[mt][nt] = __builtin_amdgcn_mfma_f32_16x16x32_bf16(pa[mt][1], vb[nt][1], o[mt][nt], 0, 0, 0);
    }

  float* op = out + (size_t)win * 32768 + h * 64;
#pragma unroll
  for (int mt = 0; mt < 4; ++mt)
#pragma unroll
    for (int nt = 0; nt < 4; ++nt)
#pragma unroll
      for (int rr = 0; rr < 4; ++rr)
        op[(size_t)(mt * 16 + hi * 4 + rr) * 512 + nt * 16 + lr] = o[mt][nt][rr];
}

extern "C" void kernel_launch(void* const* d_in, const int* in_sizes, int n_in,
                              void* d_out, int out_size, void* d_ws, size_t ws_size,
                              hipStream_t stream) {
  const float* x     = (const float*)d_in[0];
  const float* Wq    = (const float*)d_in[1];
  const float* bq    = (const float*)d_in[2];
  const float* Wk    = (const float*)d_in[3];
  const float* bk    = (const float*)d_in[4];
  const float* Wv    = (const float*)d_in[5];
  const float* bv    = (const float*)d_in[6];
  const float* Bbias = (const float*)d_in[7];
  float* out = (float*)d_out;

  // ws: Wc@0 | Xb@2MiB | Q@36MiB | K@68MiB | V^T@100MiB
  unsigned short* Wc = (unsigned short*)d_ws;
  unsigned short* Xb = (unsigned short*)((char*)d_ws + ((size_t)2 << 20));
  unsigned short* Q  = (unsigned short*)((char*)d_ws + ((size_t)36 << 20));
  unsigned short* K  = (unsigned short*)((char*)d_ws + ((size_t)68 << 20));
  unsigned short* V  = (unsigned short*)((char*)d_ws + ((size_t)100 << 20));

  prep_convert<<<dim3(8576), dim3(256), 0, stream>>>(x, Wq, Wk, Wv, Xb, Wc);
  qkv_gemm_256<<<dim3(768), dim3(512), 0, stream>>>(Xb, Wc, bq, bk, bv, Q, K, V);
  attn_win<<<dim3(4096), dim3(64), 0, stream>>>(Q, K, V, Bbias, out);
}

// Round 13
// 111.746 us; speedup vs baseline: 4.7191x; 1.0135x over previous
//
#include <hip/hip_runtime.h>
#include <hip/hip_bf16.h>

// B=8, C=512, H=W=64, NH=8, HD=64, WIN=64, NW=64.
// Token matrix = x viewed as [32768][512] fp32 (raw reshape).
//   phase 0: convert X -> bf16, W{q,k,v} -> Wcat bf16 [1536][512]
//   phase 1: QKV GEMM M=32768 K=512 N=1536 — 256x256 tile, BK=64, 8 waves,
//            drift schedule (1 barrier/K-tile), T2 st_16x32 swizzle,
//            T5 setprio around MFMA bursts, LDS-staged coalesced epilogue.
//   phase 2: attention, 4 heads/block (256 thr), wave-private P, no barriers.
// ws: Wc@0 | Xb@2MiB | Q@36MiB | K@68MiB | V^T@100MiB (132MiB; fits).
// r11 lesson: no __threadfence producer/consumer fusion (XCD L2 flush, 527us).

typedef __attribute__((ext_vector_type(8))) short bf16x8;
typedef __attribute__((ext_vector_type(4))) float f32x4;

#define GLDS(gp, lp) __builtin_amdgcn_global_load_lds( \
    (const __attribute__((address_space(1))) unsigned int*)(gp), \
    (__attribute__((address_space(3))) unsigned int*)(lp), 16, 0, 0)

__device__ __forceinline__ unsigned short f2bf(float f) {
  union { __hip_bfloat16 h; unsigned short u; } v;
  v.h = __float2bfloat16(f);               // v_cvt_pk_bf16_f32 (RNE)
  return v.u;
}

// ---------- prep: X fp32->bf16 and W{q,k,v} -> Wcat bf16 ----------
__global__ __launch_bounds__(256) void prep_convert(
    const float* __restrict__ X, const float* __restrict__ Wq,
    const float* __restrict__ Wk, const float* __restrict__ Wv,
    unsigned short* __restrict__ Xb, unsigned short* __restrict__ Wc) {
  const unsigned int i = blockIdx.x * 256 + threadIdx.x;
  const float* src;
  unsigned short* dst;
  if (i < 2097152u) {                       // X: 16.7M floats, 8 per thread
    src = X + (size_t)i * 8;
    dst = Xb + (size_t)i * 8;
  } else {                                  // Wcat: [1536][512]
    const unsigned int j = i - 2097152u;    // < 98304
    const unsigned int e = j * 8;
    const unsigned int n = e >> 9, kk = e & 511;
    src = ((n < 512) ? Wq : (n < 1024 ? Wk : Wv)) + (size_t)(n & 511) * 512 + kk;
    dst = Wc + (size_t)n * 512 + kk;
  }
  float4 f0 = *(const float4*)(src);
  float4 f1 = *(const float4*)(src + 4);
  __align__(16) unsigned short u[8];
  u[0] = f2bf(f0.x); u[1] = f2bf(f0.y); u[2] = f2bf(f0.z); u[3] = f2bf(f0.w);
  u[4] = f2bf(f1.x); u[5] = f2bf(f1.y); u[6] = f2bf(f1.z); u[7] = f2bf(f1.w);
  *(bf16x8*)(dst) = *(const bf16x8*)(u);
}

// ---------- QKV GEMM: 256x256 tile, BK=64, 8 waves, drift + setprio ----------
__global__ __launch_bounds__(512, 2) void qkv_gemm_256(
    const unsigned short* __restrict__ Xb, const unsigned short* __restrict__ Wc,
    const float* __restrict__ bq, const float* __restrict__ bk,
    const float* __restrict__ bv,
    unsigned short* __restrict__ Qo, unsigned short* __restrict__ Ko,
    unsigned short* __restrict__ Vo) {
  __shared__ __align__(16) char LDS[131072];

  const int tid  = threadIdx.x;
  const int lane = tid & 63;
  const int wid  = tid >> 6;
  const int wm = wid >> 2, wn = wid & 3;   // 2(M) x 4(N); wave tile 128x64

  // XCD-chunked swizzle: 768 = 8 x 96 works; n-tiles fastest within a chunk.
  const int work = (int)(blockIdx.x & 7) * 96 + (int)(blockIdx.x >> 3);
  const int bx = work % 6, by = work / 6;
  const int n0 = bx * 256, m0 = by * 256;

  // --- staging addressing (linear LDS dest; inverse-swizzled global source) ---
  const int lcol  = ((lane & 3) * 8) ^ ((lane >= 32) ? 16 : 0);   // elements
  const int arow0 = (wid >> 1) * 16 + (lane >> 2);                // 0..63
  const int acol0 = (wid & 1) * 32 + lcol;

#define STAGE_A(half, tt) do { \
    const unsigned short* g = Xb + (size_t)(m0 + (half) * 128 + arow0) * 512 + (tt) * 64 + acol0; \
    char* l = LDS + ((tt) & 1) * 32768 + (half) * 16384 + wid * 1024; \
    GLDS(g, l); \
    GLDS(g + 64 * 512, l + 8192); \
  } while (0)

#define STAGE_B(half, tt) do { \
    const unsigned short* g = Wc + (size_t)(n0 + (half) * 128 + arow0) * 512 + (tt) * 64 + acol0; \
    char* l = LDS + 65536 + ((tt) & 1) * 32768 + (half) * 16384 + wid * 1024; \
    GLDS(g, l); \
    GLDS(g + 64 * 512, l + 8192); \
  } while (0)

  // --- fragment-read addressing (st_16x32-swizzled; validated r3-r12) ---
  const int sloff = (((lane & 15) * 64) + ((lane >> 4) * 16)) ^ ((lane & 8) ? 32 : 0);
  char* const Ab = LDS + wm * 16384 + sloff;
  char* const Bb2 = LDS + 65536 + (wn >> 1) * 16384 + sloff;
  const int bfr = (wn & 1) * 4;   // B frag index base within half

  f32x4 acc[8][4];
#pragma unroll
  for (int i = 0; i < 8; ++i)
#pragma unroll
    for (int j = 0; j < 4; ++j) acc[i][j] = (f32x4){0.f, 0.f, 0.f, 0.f};

  // prologue: stage tile 0 into buf0
  STAGE_A(0, 0); STAGE_A(1, 0); STAGE_B(0, 0); STAGE_B(1, 0);
  asm volatile("s_waitcnt vmcnt(0)" ::: "memory");
  __builtin_amdgcn_s_barrier();

  for (int t = 0; t < 8; ++t) {
    const int bo = (t & 1) * 32768;
    if (t + 1 < 8) {                        // stage next tile into free buffer
      STAGE_A(0, t + 1); STAGE_A(1, t + 1);
      STAGE_B(0, t + 1); STAGE_B(1, t + 1);
    }
    {                                       // full-tile compute, no barriers
      bf16x8 a[8], b[4];
#pragma unroll
      for (int mi = 0; mi < 8; ++mi)
        a[mi] = *(const bf16x8*)(Ab + bo + mi * 2048);
#pragma unroll
      for (int ni = 0; ni < 4; ++ni)
        b[ni] = *(const bf16x8*)(Bb2 + bo + (bfr + ni) * 2048);
      __builtin_amdgcn_s_setprio(1);        // T5: favor MFMA-entering wave
#pragma unroll
      for (int mi = 0; mi < 8; ++mi)
#pragma unroll
        for (int ni = 0; ni < 4; ++ni)
          acc[mi][ni] = __builtin_amdgcn_mfma_f32_16x16x32_bf16(
              a[mi], b[ni], acc[mi][ni], 0, 0, 0);
      __builtin_amdgcn_s_setprio(0);
#pragma unroll
      for (int mi = 0; mi < 8; ++mi)
        a[mi] = *(const bf16x8*)(Ab + bo + mi * 2048 + 1024);
#pragma unroll
      for (int ni = 0; ni < 4; ++ni)
        b[ni] = *(const bf16x8*)(Bb2 + bo + (bfr + ni) * 2048 + 1024);
      __builtin_amdgcn_s_setprio(1);
#pragma unroll
      for (int mi = 0; mi < 8; ++mi)
#pragma unroll
        for (int ni = 0; ni < 4; ++ni)
          acc[mi][ni] = __builtin_amdgcn_mfma_f32_16x16x32_bf16(
              a[mi], b[ni], acc[mi][ni], 0, 0, 0);
      __builtin_amdgcn_s_setprio(0);
    }
    if (t + 1 < 8) asm volatile("s_waitcnt vmcnt(0)" ::: "memory");
    __builtin_amdgcn_s_barrier();
  }

  // ---- epilogue: LDS-staged, coalesced 16B stores (validated r4-r12) ----
  {
    const int p = n0 >> 9;                  // 0:Q 1:K 2:V (256-tile never spans)
    const float* bias = (p == 0) ? bq : (p == 1) ? bk : bv;
    const float qs = (p == 0) ? 0.125f : 1.0f;
    const int hi = lane >> 4, lr = lane & 15;
    const int h = ((n0 & 511) + wn * 64) >> 6;
    char* const scr = LDS + wid * 8192;
    float bsv[4];
#pragma unroll
    for (int ni = 0; ni < 4; ++ni)
      bsv[ni] = bias[(n0 & 511) + wn * 64 + ni * 16 + lr];

#pragma unroll
    for (int wh = 0; wh < 2; ++wh) {
      asm volatile("s_waitcnt lgkmcnt(0)" ::: "memory");  // WAR vs prev reads
      __builtin_amdgcn_sched_barrier(0);
      if (p < 2) {
        // T[t][d]: thread writes (t = f*16+hi*4+rr, d = ni*16+lr)
#pragma unroll
        for (int f = 0; f < 4; ++f)
#pragma unroll
          for (int ni = 0; ni < 4; ++ni) {
            const int d = ni * 16 + lr;
#pragma unroll
            for (int rr = 0; rr < 4; ++rr) {
              const int t = f * 16 + hi * 4 + rr;
              const int off = t * 64 + (d ^ ((t & 7) << 3));
              *(unsigned short*)(scr + off * 2) =
                  f2bf((acc[wh * 4 + f][ni][rr] + bsv[ni]) * qs);
            }
          }
      } else {
        // T'[d][t]: thread packs 4 consecutive t (rr) at fixed d -> b64
#pragma unroll
        for (int f = 0; f < 4; ++f)
#pragma unroll
          for (int ni = 0; ni < 4; ++ni) {
            const int d = ni * 16 + lr;
            const int t0 = f * 16 + hi * 4;
            ushort4 pk;
            pk.x = f2bf(acc[wh * 4 + f][ni][0] + bsv[ni]);
            pk.y = f2bf(acc[wh * 4 + f][ni][1] + bsv[ni]);
            pk.z = f2bf(acc[wh * 4 + f][ni][2] + bsv[ni]);
            pk.w = f2bf(acc[wh * 4 + f][ni][3] + bsv[ni]);
            const int off = d * 64 + (t0 ^ ((d & 7) << 3));
            *(ushort4*)(scr + off * 2) = pk;
          }
      }
      asm volatile("s_waitcnt lgkmcnt(0)" ::: "memory");  // writes -> readable
      __builtin_amdgcn_sched_barrier(0);
      const int win = (m0 + wm * 128 + wh * 64) >> 6;
      unsigned short* dst =
          ((p == 0) ? Qo : (p == 1) ? Ko : Vo) + (size_t)(win * 8 + h) * 4096;
#pragma unroll
      for (int i = 0; i < 8; ++i) {
        const int r = i * 8 + (lane >> 3);
        const int c = lane & 7;
        const int off = r * 64 + ((c ^ (r & 7)) * 8);
        bf16x8 row = *(const bf16x8*)(scr + off * 2);   // ds_read_b128
        *(bf16x8*)(dst + r * 64 + c * 8) = row;         // coalesced 16B store
      }
    }
  }
#undef STAGE_A
#undef STAGE_B
}

// ---------- attention: 4 heads/block, 1 wave/head, wave-private P ----------
__global__ __launch_bounds__(256) void attn_win4(
    const unsigned short* __restrict__ Qp, const unsigned short* __restrict__ Kp,
    const unsigned short* __restrict__ Vp, const float* __restrict__ Bb,
    float* __restrict__ out) {
  __shared__ __align__(16) unsigned short Pbuf[4 * 64 * 72];
  const int lane = threadIdx.x & 63;
  const int wid  = threadIdx.x >> 6;
  const int win = blockIdx.x >> 1;
  const int h   = (blockIdx.x & 1) * 4 + wid;
  const size_t base = (size_t)(win * 8 + h) * 4096;
  const unsigned short* q = Qp + base;
  const unsigned short* k = Kp + base;
  const unsigned short* v = Vp + base;   // V^T: [d][t]
  unsigned short* const P = Pbuf + wid * 4608;
  const int lr = lane & 15;
  const int hi = lane >> 4;

  bf16x8 qa[4][2], kb[4][2];
#pragma unroll
  for (int mt = 0; mt < 4; ++mt)
#pragma unroll
    for (int ks = 0; ks < 2; ++ks)
      qa[mt][ks] = *(const bf16x8*)(q + (size_t)(mt * 16 + lr) * 64 + ks * 32 + hi * 8);
#pragma unroll
  for (int nt = 0; nt < 4; ++nt)
#pragma unroll
    for (int ks = 0; ks < 2; ++ks)
      kb[nt][ks] = *(const bf16x8*)(k + (size_t)(nt * 16 + lr) * 64 + ks * 32 + hi * 8);

  f32x4 s[4][4];
#pragma unroll
  for (int mt = 0; mt < 4; ++mt)
#pragma unroll
    for (int nt = 0; nt < 4; ++nt) {
      s[mt][nt] = (f32x4){0.f, 0.f, 0.f, 0.f};
      s[mt][nt] = __builtin_amdgcn_mfma_f32_16x16x32_bf16(qa[mt][0], kb[nt][0], s[mt][nt], 0, 0, 0);
      s[mt][nt] = __builtin_amdgcn_mfma_f32_16x16x32_bf16(qa[mt][1], kb[nt][1], s[mt][nt], 0, 0, 0);
    }

#pragma unroll
  for (int mt = 0; mt < 4; ++mt)
#pragma unroll
    for (int nt = 0; nt < 4; ++nt)
#pragma unroll
      for (int rr = 0; rr < 4; ++rr)
        s[mt][nt][rr] += Bb[(mt * 16 + hi * 4 + rr) * 64 + nt * 16 + lr];

  float inv[4][4];
#pragma unroll
  for (int mt = 0; mt < 4; ++mt)
#pragma unroll
    for (int rr = 0; rr < 4; ++rr) {
      float m = fmaxf(fmaxf(s[mt][0][rr], s[mt][1][rr]),
                      fmaxf(s[mt][2][rr], s[mt][3][rr]));
      m = fmaxf(m, __shfl_xor(m, 1));
      m = fmaxf(m, __shfl_xor(m, 2));
      m = fmaxf(m, __shfl_xor(m, 4));
      m = fmaxf(m, __shfl_xor(m, 8));
      float sum = 0.f;
#pragma unroll
      for (int nt = 0; nt < 4; ++nt) {
        float e = __expf(s[mt][nt][rr] - m);
        s[mt][nt][rr] = e;
        sum += e;
      }
      sum += __shfl_xor(sum, 1);
      sum += __shfl_xor(sum, 2);
      sum += __shfl_xor(sum, 4);
      sum += __shfl_xor(sum, 8);
      inv[mt][rr] = 1.0f / sum;
    }

#pragma unroll
  for (int mt = 0; mt < 4; ++mt)
#pragma unroll
    for (int nt = 0; nt < 4; ++nt)
#pragma unroll
      for (int rr = 0; rr < 4; ++rr)
        P[(mt * 16 + hi * 4 + rr) * 72 + nt * 16 + lr] =
            f2bf(s[mt][nt][rr] * inv[mt][rr]);
  // wave-private P: wave-local wait is sufficient (no block barrier)
  asm volatile("s_waitcnt lgkmcnt(0)" ::: "memory");
  __builtin_amdgcn_sched_barrier(0);

  bf16x8 pa[4][2], vb[4][2];
#pragma unroll
  for (int mt = 0; mt < 4; ++mt)
#pragma unroll
    for (int ks = 0; ks < 2; ++ks)
      pa[mt][ks] = *(const bf16x8*)(&P[(mt * 16 + lr) * 72 + ks * 32 + hi * 8]);
#pragma unroll
  for (int nt = 0; nt < 4; ++nt)
#pragma unroll
    for (int ks = 0; ks < 2; ++ks)
      vb[nt][ks] = *(const bf16x8*)(v + (size_t)(nt * 16 + lr) * 64 + ks * 32 + hi * 8);

  f32x4 o[4][4];
#pragma unroll
  for (int mt = 0; mt < 4; ++mt)
#pragma unroll
    for (int nt = 0; nt < 4; ++nt) {
      o[mt][nt] = (f32x4){0.f, 0.f, 0.f, 0.f};
      o[mt][nt] = __builtin_amdgcn_mfma_f32_16x16x32_bf16(pa[mt][0], vb[nt][0], o[mt][nt], 0, 0, 0);
      o[mt][nt] = __builtin_amdgcn_mfma_f32_16x16x32_bf16(pa[mt][1], vb[nt][1], o[mt][nt], 0, 0, 0);
    }

  float* op = out + (size_t)win * 32768 + h * 64;
#pragma unroll
  for (int mt = 0; mt < 4; ++mt)
#pragma unroll
    for (int nt = 0; nt < 4; ++nt)
#pragma unroll
      for (int rr = 0; rr < 4; ++rr)
        op[(size_t)(mt * 16 + hi * 4 + rr) * 512 + nt * 16 + lr] = o[mt][nt][rr];
}

extern "C" void kernel_launch(void* const* d_in, const int* in_sizes, int n_in,
                              void* d_out, int out_size, void* d_ws, size_t ws_size,
                              hipStream_t stream) {
  const float* x     = (const float*)d_in[0];
  const float* Wq    = (const float*)d_in[1];
  const float* bq    = (const float*)d_in[2];
  const float* Wk    = (const float*)d_in[3];
  const float* bk    = (const float*)d_in[4];
  const float* Wv    = (const float*)d_in[5];
  const float* bv    = (const float*)d_in[6];
  const float* Bbias = (const float*)d_in[7];
  float* out = (float*)d_out;

  // ws: Wc@0 | Xb@2MiB | Q@36MiB | K@68MiB | V^T@100MiB
  unsigned short* Wc = (unsigned short*)d_ws;
  unsigned short* Xb = (unsigned short*)((char*)d_ws + ((size_t)2 << 20));
  unsigned short* Q  = (unsigned short*)((char*)d_ws + ((size_t)36 << 20));
  unsigned short* K  = (unsigned short*)((char*)d_ws + ((size_t)68 << 20));
  unsigned short* V  = (unsigned short*)((char*)d_ws + ((size_t)100 << 20));

  prep_convert<<<dim3(8576), dim3(256), 0, stream>>>(x, Wq, Wk, Wv, Xb, Wc);
  qkv_gemm_256<<<dim3(768), dim3(512), 0, stream>>>(Xb, Wc, bq, bk, bv, Q, K, V);
  attn_win4<<<dim3(1024), dim3(256), 0, stream>>>(Q, K, V, Bbias, out);
}